// Round 2
// baseline (646.011 us; speedup 1.0000x reference)
//
#include <hip/hip_runtime.h>

typedef __attribute__((ext_vector_type(8))) short bf16x8;
typedef __attribute__((ext_vector_type(4))) float f32x4;
typedef __attribute__((ext_vector_type(4))) short s16x4;

#define MFMA16(a, b, c) __builtin_amdgcn_mfma_f32_16x16x32_bf16((a), (b), (c), 0, 0, 0)

__device__ __forceinline__ short f2bf(float f) {
    union { float f; unsigned u; } v; v.f = f;
    return (short)((v.u + 0x7FFFu + ((v.u >> 16) & 1u)) >> 16);  // RNE
}
__device__ __forceinline__ s16x4 cvt4(f32x4 v) {
    s16x4 r; r[0] = f2bf(v[0]); r[1] = f2bf(v[1]); r[2] = f2bf(v[2]); r[3] = f2bf(v[3]); return r;
}
__device__ __forceinline__ f32x4 fzero4() { f32x4 z; z[0]=0.f; z[1]=0.f; z[2]=0.f; z[3]=0.f; return z; }

union bfrag { bf16x8 v; s16x4 h[2]; };

// LDS layout (byte offsets). Strides 264/72 shorts keep 16B alignment and <=2-way banks.
//   XA  shorts [0,18432)      : X bf16 [64][264] -> P scratch [4][64][72]
//   Qs  shorts [18432,35328)  : Q[64][264] -> attn_out[64][264]
//   Ks  shorts [35328,52224)  : K[64][264]   (later overlaid by f32 out stage)
//   VT  shorts [52224,70656)  : V^T [256][72] (later overlaid by f32 out stage)
//   SG  floats at short-idx 35328: out stage f32 [64][260] = 66560 B  (bytes [70656,137216))
#define SMEM_BYTES 141312

__global__ __launch_bounds__(256, 1)
void ga2d_kernel(const float* __restrict__ x,
                 const float* __restrict__ wqkv,
                 const float* __restrict__ bqkv,
                 const float* __restrict__ wproj,
                 const float* __restrict__ bproj,
                 float* __restrict__ out)
{
    extern __shared__ short smem[];
    short* XA = smem;
    short* Qs = smem + 18432;
    short* Ks = smem + 35328;
    short* VT = smem + 52224;
    float* SG = (float*)(smem + 35328);

    const int tid  = threadIdx.x;
    const int w    = tid >> 6;
    const int lane = tid & 63;
    const int l16  = lane & 15;
    const int q4   = lane >> 4;

    const int blk = blockIdx.x;          // (b, hp, wp)
    const int bb  = blk >> 6;
    const int hp  = (blk >> 3) & 7;
    const int wp  = blk & 7;
    const size_t gbase = (size_t)bb * 64 * 64 * 256;

    // ---------------- phase 0: gather X (f32) -> bf16 LDS ----------------
    #pragma unroll
    for (int i = 0; i < 16; ++i) {
        int id  = i * 256 + tid;
        int tok = id >> 6, c4 = id & 63;
        int hr  = (tok >> 3) * 8 + hp;
        int wc  = (tok & 7) * 8 + wp;
        f32x4 v = *(const f32x4*)(x + gbase + ((size_t)hr * 64 + wc) * 256 + c4 * 4);
        *(s16x4*)(XA + tok * 264 + c4 * 4) = cvt4(v);
    }
    __syncthreads();

    // ---------------- phase 1: QKV projection (M=64,N=768,K=256) ----------------
    #pragma unroll
    for (int g3 = 0; g3 < 3; ++g3) {
        const int nt0 = w * 12 + g3 * 4;
        f32x4 acc[4][4];
        #pragma unroll
        for (int n = 0; n < 4; ++n)
            #pragma unroll
            for (int m = 0; m < 4; ++m) acc[n][m] = fzero4();

        #pragma unroll
        for (int k = 0; k < 8; ++k) {
            const int koff = k * 32 + q4 * 8;
            bf16x8 a[4]; bfrag bw[4];
            #pragma unroll
            for (int m = 0; m < 4; ++m)
                a[m] = *(const bf16x8*)(XA + (m * 16 + l16) * 264 + koff);
            #pragma unroll
            for (int n = 0; n < 4; ++n) {
                const float* wp_ = wqkv + (size_t)((nt0 + n) * 16 + l16) * 256 + koff;
                bw[n].h[0] = cvt4(*(const f32x4*)(wp_));
                bw[n].h[1] = cvt4(*(const f32x4*)(wp_ + 4));
            }
            #pragma unroll
            for (int n = 0; n < 4; ++n)
                #pragma unroll
                for (int m = 0; m < 4; ++m)
                    acc[n][m] = MFMA16(a[m], bw[n].v, acc[n][m]);
        }
        // scatter-store: Q/K row-major, V transposed (packed b64 along tokens)
        #pragma unroll
        for (int n = 0; n < 4; ++n) {
            const int col  = (nt0 + n) * 16 + l16;
            const float bi = bqkv[col];
            #pragma unroll
            for (int m = 0; m < 4; ++m) {
                const int row0 = m * 16 + q4 * 4;
                if (col < 256) {
                    #pragma unroll
                    for (int r = 0; r < 4; ++r)
                        Qs[(row0 + r) * 264 + col] = f2bf(acc[n][m][r] + bi);
                } else if (col < 512) {
                    #pragma unroll
                    for (int r = 0; r < 4; ++r)
                        Ks[(row0 + r) * 264 + (col - 256)] = f2bf(acc[n][m][r] + bi);
                } else {
                    s16x4 pk;
                    #pragma unroll
                    for (int r = 0; r < 4; ++r) pk[r] = f2bf(acc[n][m][r] + bi);
                    *(s16x4*)(VT + (col - 512) * 72 + row0) = pk;
                }
            }
        }
    }
    __syncthreads();

    // ---------------- phase 2: attention, 2 heads per wave ----------------
    short* PW = XA + w * (64 * 72);            // per-wave P scratch
    const float kscl = 0.25503546f;            // log2(e) / sqrt(32)
    for (int hi = 0; hi < 2; ++hi) {
        const int hh = w * 2 + hi;
        bf16x8 qa[4], kb[4];
        #pragma unroll
        for (int m = 0; m < 4; ++m)
            qa[m] = *(const bf16x8*)(Qs + (m * 16 + l16) * 264 + hh * 32 + q4 * 8);
        #pragma unroll
        for (int n = 0; n < 4; ++n)
            kb[n] = *(const bf16x8*)(Ks + (n * 16 + l16) * 264 + hh * 32 + q4 * 8);
        f32x4 s[4][4];
        #pragma unroll
        for (int m = 0; m < 4; ++m)
            #pragma unroll
            for (int n = 0; n < 4; ++n)
                s[m][n] = MFMA16(qa[m], kb[n], fzero4());

        float rinv[4][4];
        #pragma unroll
        for (int m = 0; m < 4; ++m) {
            #pragma unroll
            for (int r = 0; r < 4; ++r) {
                float v = fmaxf(fmaxf(s[m][0][r], s[m][1][r]), fmaxf(s[m][2][r], s[m][3][r]));
                v = fmaxf(v, __shfl_xor(v, 1));
                v = fmaxf(v, __shfl_xor(v, 2));
                v = fmaxf(v, __shfl_xor(v, 4));
                v = fmaxf(v, __shfl_xor(v, 8));
                float t = 0.f;
                #pragma unroll
                for (int n = 0; n < 4; ++n) {
                    s[m][n][r] = exp2f((s[m][n][r] - v) * kscl);
                    t += s[m][n][r];
                }
                t += __shfl_xor(t, 1);
                t += __shfl_xor(t, 2);
                t += __shfl_xor(t, 4);
                t += __shfl_xor(t, 8);
                rinv[m][r] = 1.0f / t;     // defer division to epilogue
            }
        }
        // P: C-layout -> A-layout via per-wave LDS round trip
        #pragma unroll
        for (int m = 0; m < 4; ++m)
            #pragma unroll
            for (int n = 0; n < 4; ++n)
                #pragma unroll
                for (int r = 0; r < 4; ++r)
                    PW[(m * 16 + q4 * 4 + r) * 72 + n * 16 + l16] = f2bf(s[m][n][r]);
        __syncthreads();   // uniform across waves

        // O = P V
        f32x4 o[4][2];
        #pragma unroll
        for (int m = 0; m < 4; ++m) { o[m][0] = fzero4(); o[m][1] = fzero4(); }
        #pragma unroll
        for (int kt = 0; kt < 2; ++kt) {
            bf16x8 pa[4], vb[2];
            #pragma unroll
            for (int m = 0; m < 4; ++m)
                pa[m] = *(const bf16x8*)(PW + (m * 16 + l16) * 72 + kt * 32 + q4 * 8);
            #pragma unroll
            for (int dt = 0; dt < 2; ++dt)
                vb[dt] = *(const bf16x8*)(VT + (hh * 32 + dt * 16 + l16) * 72 + kt * 32 + q4 * 8);
            #pragma unroll
            for (int m = 0; m < 4; ++m)
                #pragma unroll
                for (int dt = 0; dt < 2; ++dt)
                    o[m][dt] = MFMA16(pa[m], vb[dt], o[m][dt]);
        }
        // attn_out -> Qs (wave exclusively owns cols [64w,64w+64))
        #pragma unroll
        for (int m = 0; m < 4; ++m)
            #pragma unroll
            for (int dt = 0; dt < 2; ++dt)
                #pragma unroll
                for (int r = 0; r < 4; ++r)
                    Qs[(m * 16 + q4 * 4 + r) * 264 + hh * 32 + dt * 16 + l16] =
                        f2bf(o[m][dt][r] * rinv[m][r]);
    }
    __syncthreads();

    // ---------------- phase 3: out projection (M=64,N=256,K=256), f32 stage ----------------
    {
        f32x4 pc[4][4];
        #pragma unroll
        for (int j = 0; j < 4; ++j)
            #pragma unroll
            for (int m = 0; m < 4; ++m) pc[j][m] = fzero4();
        #pragma unroll
        for (int k = 0; k < 8; ++k) {
            const int koff = k * 32 + q4 * 8;
            bf16x8 a[4]; bfrag bw[4];
            #pragma unroll
            for (int m = 0; m < 4; ++m)
                a[m] = *(const bf16x8*)(Qs + (m * 16 + l16) * 264 + koff);
            #pragma unroll
            for (int j = 0; j < 4; ++j) {
                const float* wp_ = wproj + (size_t)((w * 4 + j) * 16 + l16) * 256 + koff;
                bw[j].h[0] = cvt4(*(const f32x4*)(wp_));
                bw[j].h[1] = cvt4(*(const f32x4*)(wp_ + 4));
            }
            #pragma unroll
            for (int j = 0; j < 4; ++j)
                #pragma unroll
                for (int m = 0; m < 4; ++m)
                    pc[j][m] = MFMA16(a[m], bw[j].v, pc[j][m]);
        }
        __syncthreads();   // Ks/VT dead; SG overlays them
        #pragma unroll
        for (int j = 0; j < 4; ++j) {
            const int col  = (w * 4 + j) * 16 + l16;
            const float bi = bproj[col];
            #pragma unroll
            for (int m = 0; m < 4; ++m)
                #pragma unroll
                for (int r = 0; r < 4; ++r)
                    SG[(m * 16 + q4 * 4 + r) * 260 + col] = pc[j][m][r] + bi;
        }
    }
    __syncthreads();

    // ---------------- phase 4: coalesced f32 scatter writeback ----------------
    #pragma unroll
    for (int i = 0; i < 16; ++i) {
        int id  = i * 256 + tid;
        int tok = id >> 6, c4 = id & 63;
        int hr  = (tok >> 3) * 8 + hp;
        int wc  = (tok & 7) * 8 + wp;
        f32x4 v = *(const f32x4*)(SG + tok * 260 + c4 * 4);
        *(f32x4*)(out + gbase + ((size_t)hr * 64 + wc) * 256 + c4 * 4) = v;
    }
}

extern "C" void kernel_launch(void* const* d_in, const int* in_sizes, int n_in,
                              void* d_out, int out_size, void* d_ws, size_t ws_size,
                              hipStream_t stream) {
    const float* x     = (const float*)d_in[0];
    const float* wqkv  = (const float*)d_in[1];
    const float* bqkv  = (const float*)d_in[2];
    const float* wproj = (const float*)d_in[3];
    const float* bproj = (const float*)d_in[4];
    float*       out   = (float*)d_out;

    hipFuncSetAttribute(reinterpret_cast<const void*>(ga2d_kernel),
                        hipFuncAttributeMaxDynamicSharedMemorySize, SMEM_BYTES);
    ga2d_kernel<<<2048, 256, SMEM_BYTES, stream>>>(x, wqkv, bqkv, wproj, bproj, out);
}

// Round 3
// 371.583 us; speedup vs baseline: 1.7385x; 1.7385x over previous
//
#include <hip/hip_runtime.h>

typedef __attribute__((ext_vector_type(8))) short bf16x8;
typedef __attribute__((ext_vector_type(4))) float f32x4;
typedef __attribute__((ext_vector_type(4))) short s16x4;

#define MFMA16(a, b, c) __builtin_amdgcn_mfma_f32_16x16x32_bf16((a), (b), (c), 0, 0, 0)

__device__ __forceinline__ short f2bf(float f) {
    union { float f; unsigned u; } v; v.f = f;
    return (short)((v.u + 0x7FFFu + ((v.u >> 16) & 1u)) >> 16);  // RNE
}
__device__ __forceinline__ s16x4 cvt4(f32x4 v) {
    s16x4 r; r[0] = f2bf(v[0]); r[1] = f2bf(v[1]); r[2] = f2bf(v[2]); r[3] = f2bf(v[3]); return r;
}
__device__ __forceinline__ f32x4 fzero4() { f32x4 z; z[0]=0.f; z[1]=0.f; z[2]=0.f; z[3]=0.f; return z; }

// ws layout (shorts): [0,196608) wqkv bf16 row-major [768][256]; [196608,262144) wproj bf16 [256][256]
__global__ __launch_bounds__(256, 1)
void convw_kernel(const float* __restrict__ wqkv, const float* __restrict__ wproj,
                  short* __restrict__ wsb)
{
    int i = (blockIdx.x * 256 + threadIdx.x) * 8;          // 128 blocks x 256 thr x 8 = 262144
    const float* src = (i < 196608) ? (wqkv + i) : (wproj + (i - 196608));
    *(s16x4*)(wsb + i)     = cvt4(*(const f32x4*)(src));
    *(s16x4*)(wsb + i + 4) = cvt4(*(const f32x4*)(src + 4));
}

// LDS (shorts): XA [64][264] = 16896 (X bf16 -> attn_out bf16)
//               SW per-wave scratch [64][72] = 4608 x 4 waves
#define SMEM_BYTES 70656

__global__ __launch_bounds__(256, 2)
void ga2d_kernel(const float* __restrict__ x,
                 const short* __restrict__ wsb,
                 const float* __restrict__ bqkv,
                 const float* __restrict__ bproj,
                 float* __restrict__ out)
{
    extern __shared__ short smem[];
    short* XA = smem;                                   // [64][264]
    const int tid  = threadIdx.x;
    const int w    = tid >> 6;
    const int lane = tid & 63;
    const int l16  = lane & 15;
    const int q4   = lane >> 4;
    short* SW = smem + 16896 + w * 4608;                // per-wave [64][72]

    const int blk = blockIdx.x;                         // (b, hp, wp)
    const int bb  = blk >> 6;
    const int hp  = (blk >> 3) & 7;
    const int wp  = blk & 7;
    const size_t gbase = (size_t)bb * 64 * 64 * 256;

    // ---------------- phase 0: gather X (f32) -> bf16 LDS ----------------
    #pragma unroll
    for (int i = 0; i < 16; ++i) {
        int id  = i * 256 + tid;
        int tok = id >> 6, c4 = id & 63;
        int hr  = (tok >> 3) * 8 + hp;
        int wc  = (tok & 7) * 8 + wp;
        f32x4 v = *(const f32x4*)(x + gbase + ((size_t)hr * 64 + wc) * 256 + c4 * 4);
        *(s16x4*)(XA + tok * 264 + c4 * 4) = cvt4(v);
    }
    __syncthreads();

    // ---------------- phase 1: head-aligned QKV. wave w owns cols [64w,64w+64) of Q,K,V ----
    bf16x8 qa[2][4], kb[2][4], vb[2][2][2];   // per-head frags kept in registers
    #pragma unroll
    for (int g3 = 0; g3 < 3; ++g3) {          // 0:Q 1:K 2:V
        const short* WB = wsb + (size_t)(g3 * 256 + w * 64) * 256;
        f32x4 acc[4][4];
        #pragma unroll
        for (int n = 0; n < 4; ++n)
            #pragma unroll
            for (int m = 0; m < 4; ++m) acc[n][m] = fzero4();
        #pragma unroll
        for (int k = 0; k < 8; ++k) {
            const int koff = k * 32 + q4 * 8;
            bf16x8 a[4], bw[4];
            #pragma unroll
            for (int m = 0; m < 4; ++m)
                a[m] = *(const bf16x8*)(XA + (m * 16 + l16) * 264 + koff);
            #pragma unroll
            for (int n = 0; n < 4; ++n)
                bw[n] = *(const bf16x8*)(WB + (size_t)(n * 16 + l16) * 256 + koff);
            #pragma unroll
            for (int n = 0; n < 4; ++n)
                #pragma unroll
                for (int m = 0; m < 4; ++m)
                    acc[n][m] = MFMA16(a[m], bw[n], acc[n][m]);
        }
        // bias + store to per-wave scratch
        if (g3 < 2) {                                   // Q,K: [token][col64]
            #pragma unroll
            for (int n = 0; n < 4; ++n) {
                const float bi = bqkv[g3 * 256 + w * 64 + n * 16 + l16];
                #pragma unroll
                for (int m = 0; m < 4; ++m)
                    #pragma unroll
                    for (int r = 0; r < 4; ++r)
                        SW[(m * 16 + q4 * 4 + r) * 72 + n * 16 + l16] = f2bf(acc[n][m][r] + bi);
            }
        } else {                                        // V: transposed [d64][token], packed
            #pragma unroll
            for (int n = 0; n < 4; ++n) {
                const float bi = bqkv[512 + w * 64 + n * 16 + l16];
                #pragma unroll
                for (int m = 0; m < 4; ++m) {
                    s16x4 pk;
                    #pragma unroll
                    for (int r = 0; r < 4; ++r) pk[r] = f2bf(acc[n][m][r] + bi);
                    *(s16x4*)(SW + (n * 16 + l16) * 72 + m * 16 + q4 * 4) = pk;
                }
            }
        }
        // extract MFMA fragments (intra-wave LDS round trip; no barrier needed)
        if (g3 == 0) {
            #pragma unroll
            for (int hl = 0; hl < 2; ++hl)
                #pragma unroll
                for (int m = 0; m < 4; ++m)
                    qa[hl][m] = *(const bf16x8*)(SW + (m * 16 + l16) * 72 + hl * 32 + q4 * 8);
        } else if (g3 == 1) {
            #pragma unroll
            for (int hl = 0; hl < 2; ++hl)
                #pragma unroll
                for (int n = 0; n < 4; ++n)
                    kb[hl][n] = *(const bf16x8*)(SW + (n * 16 + l16) * 72 + hl * 32 + q4 * 8);
        } else {
            #pragma unroll
            for (int hl = 0; hl < 2; ++hl)
                #pragma unroll
                for (int dt = 0; dt < 2; ++dt)
                    #pragma unroll
                    for (int kt = 0; kt < 2; ++kt)
                        vb[hl][dt][kt] = *(const bf16x8*)(SW + (hl * 32 + dt * 16 + l16) * 72 + kt * 32 + q4 * 8);
        }
    }
    __syncthreads();   // all XA (X) reads done; XA may now be overwritten with attn_out

    // ---------------- phase 2: attention, fully wave-local ----------------
    const float kscl = 0.25503546f;            // log2(e) / sqrt(32)
    #pragma unroll
    for (int hl = 0; hl < 2; ++hl) {
        f32x4 s[4][4];
        #pragma unroll
        for (int m = 0; m < 4; ++m)
            #pragma unroll
            for (int n = 0; n < 4; ++n)
                s[m][n] = MFMA16(qa[hl][m], kb[hl][n], fzero4());

        float rinv[4][4];
        #pragma unroll
        for (int m = 0; m < 4; ++m) {
            #pragma unroll
            for (int r = 0; r < 4; ++r) {
                float v = fmaxf(fmaxf(s[m][0][r], s[m][1][r]), fmaxf(s[m][2][r], s[m][3][r]));
                v = fmaxf(v, __shfl_xor(v, 1));
                v = fmaxf(v, __shfl_xor(v, 2));
                v = fmaxf(v, __shfl_xor(v, 4));
                v = fmaxf(v, __shfl_xor(v, 8));
                float t = 0.f;
                #pragma unroll
                for (int n = 0; n < 4; ++n) {
                    s[m][n][r] = exp2f((s[m][n][r] - v) * kscl);
                    t += s[m][n][r];
                }
                t += __shfl_xor(t, 1);
                t += __shfl_xor(t, 2);
                t += __shfl_xor(t, 4);
                t += __shfl_xor(t, 8);
                rinv[m][r] = 1.0f / t;         // defer division
            }
        }
        // P: C-layout -> A-layout via wave scratch (clobbers QKV scratch; frags in regs)
        #pragma unroll
        for (int m = 0; m < 4; ++m)
            #pragma unroll
            for (int n = 0; n < 4; ++n)
                #pragma unroll
                for (int r = 0; r < 4; ++r)
                    SW[(m * 16 + q4 * 4 + r) * 72 + n * 16 + l16] = f2bf(s[m][n][r]);

        f32x4 o[4][2];
        #pragma unroll
        for (int m = 0; m < 4; ++m) { o[m][0] = fzero4(); o[m][1] = fzero4(); }
        #pragma unroll
        for (int kt = 0; kt < 2; ++kt) {
            bf16x8 pa[4];
            #pragma unroll
            for (int m = 0; m < 4; ++m)
                pa[m] = *(const bf16x8*)(SW + (m * 16 + l16) * 72 + kt * 32 + q4 * 8);
            #pragma unroll
            for (int m = 0; m < 4; ++m)
                #pragma unroll
                for (int dt = 0; dt < 2; ++dt)
                    o[m][dt] = MFMA16(pa[m], vb[hl][dt][kt], o[m][dt]);
        }
        // attn_out -> XA cols [64w + 32hl, +32)
        #pragma unroll
        for (int m = 0; m < 4; ++m)
            #pragma unroll
            for (int dt = 0; dt < 2; ++dt)
                #pragma unroll
                for (int r = 0; r < 4; ++r)
                    XA[(m * 16 + q4 * 4 + r) * 264 + w * 64 + hl * 32 + dt * 16 + l16] =
                        f2bf(o[m][dt][r] * rinv[m][r]);
    }
    __syncthreads();

    // ---------------- phase 3: out projection, direct reg->global epilogue ----------------
    {
        const short* WPb = wsb + 196608 + (size_t)(w * 64) * 256;
        f32x4 pc[4][4];
        #pragma unroll
        for (int n = 0; n < 4; ++n)
            #pragma unroll
            for (int m = 0; m < 4; ++m) pc[n][m] = fzero4();
        #pragma unroll
        for (int k = 0; k < 8; ++k) {
            const int koff = k * 32 + q4 * 8;
            bf16x8 a[4], bw[4];
            #pragma unroll
            for (int m = 0; m < 4; ++m)
                a[m] = *(const bf16x8*)(XA + (m * 16 + l16) * 264 + koff);
            #pragma unroll
            for (int n = 0; n < 4; ++n)
                bw[n] = *(const bf16x8*)(WPb + (size_t)(n * 16 + l16) * 256 + koff);
            #pragma unroll
            for (int n = 0; n < 4; ++n)
                #pragma unroll
                for (int m = 0; m < 4; ++m)
                    pc[n][m] = MFMA16(a[m], bw[n], pc[n][m]);
        }
        #pragma unroll
        for (int n = 0; n < 4; ++n) {
            const int col  = w * 64 + n * 16 + l16;
            const float bi = bproj[col];
            #pragma unroll
            for (int m = 0; m < 4; ++m) {
                #pragma unroll
                for (int r = 0; r < 4; ++r) {
                    const int tok = m * 16 + q4 * 4 + r;
                    const int hr  = (tok >> 3) * 8 + hp;
                    const int wc  = (tok & 7) * 8 + wp;
                    out[gbase + ((size_t)hr * 64 + wc) * 256 + col] = pc[n][m][r] + bi;
                }
            }
        }
    }
}

extern "C" void kernel_launch(void* const* d_in, const int* in_sizes, int n_in,
                              void* d_out, int out_size, void* d_ws, size_t ws_size,
                              hipStream_t stream) {
    const float* x     = (const float*)d_in[0];
    const float* wqkv  = (const float*)d_in[1];
    const float* bqkv  = (const float*)d_in[2];
    const float* wproj = (const float*)d_in[3];
    const float* bproj = (const float*)d_in[4];
    float*       out   = (float*)d_out;
    short*       wsb   = (short*)d_ws;       // 512 KB bf16 weights

    convw_kernel<<<128, 256, 0, stream>>>(wqkv, wproj, wsb);

    hipFuncSetAttribute(reinterpret_cast<const void*>(ga2d_kernel),
                        hipFuncAttributeMaxDynamicSharedMemorySize, SMEM_BYTES);
    ga2d_kernel<<<2048, 256, SMEM_BYTES, stream>>>(x, wsb, bqkv, bproj, out);
}